// Round 3
// baseline (180.999 us; speedup 1.0000x reference)
//
#include <hip/hip_runtime.h>
#include <hip/hip_bf16.h>
#include <stdint.h>

typedef __bf16 bf16_t;
typedef __bf16 bf16x4 __attribute__((ext_vector_type(4)));
typedef __bf16 bf16x8 __attribute__((ext_vector_type(8)));
typedef float  f32x4  __attribute__((ext_vector_type(4)));

#define AS_GLOBAL __attribute__((address_space(1)))
#define AS_LDS    __attribute__((address_space(3)))

__device__ __forceinline__ void gload_lds16(const void* g, void* l) {
  __builtin_amdgcn_global_load_lds((const AS_GLOBAL void*)g,
                                   (AS_LDS void*)l, 16, 0, 0);
}

// ---------------- K0a: f32 -> bf16 elementwise (8 elems/thread) ----------------
__global__ void cvt_f32_bf16_kernel(const float* __restrict__ in,
                                    bf16_t* __restrict__ out) {
  const int i = blockIdx.x * blockDim.x + threadIdx.x;
  f32x4 v0 = *(const f32x4*)&in[(size_t)i * 8];
  f32x4 v1 = *(const f32x4*)&in[(size_t)i * 8 + 4];
  bf16x8 o;
  o[0] = (bf16_t)v0[0]; o[1] = (bf16_t)v0[1]; o[2] = (bf16_t)v0[2]; o[3] = (bf16_t)v0[3];
  o[4] = (bf16_t)v1[0]; o[5] = (bf16_t)v1[1]; o[6] = (bf16_t)v1[2]; o[7] = (bf16_t)v1[3];
  *(bf16x8*)&out[(size_t)i * 8] = o;
}

// ---------------- K0b: weight [512][512] f32 -> wT [512][512] bf16 (transpose) ----------------
__global__ void transpose_cvt_kernel(const float* __restrict__ in,
                                     bf16_t* __restrict__ out) {
  __shared__ float t[32][33];
  const int ti = blockIdx.x;  // din tile
  const int tj = blockIdx.y;  // dout tile
  const int c = threadIdx.x & 31;
  const int r0 = threadIdx.x >> 5;  // 0..7
  #pragma unroll
  for (int p = 0; p < 4; ++p) {
    int r = r0 + p * 8;
    t[r][c] = in[(size_t)(ti * 32 + r) * 512 + tj * 32 + c];
  }
  __syncthreads();
  #pragma unroll
  for (int p = 0; p < 4; ++p) {
    int r = r0 + p * 8;
    out[(size_t)(tj * 32 + r) * 512 + ti * 32 + c] = (bf16_t)t[c][r];
  }
}

// ---------------- GEMM-BT: C[m][n] = sum_k A[m][k] * Bt[n][k] ----------------
// Tile 128(M) x 64(N) x BK=64, 512 threads = 8 waves as 4M x 2N (32x32/wave).
// Grid = (M/128)*(N/64) = 512 blocks -> 2 blocks/CU; 48 KB LDS dbuf fits 2x.
// Cross-block overlap hides the per-step vmcnt(0) barrier drain (m97 mechanism).
// Swizzled LDS layout: 16B chunk c (=k>>3) of row r lives at slot c ^ (r&7).
// B staged via global_load_lds (linear dest) with SOURCE chunk pre-swizzled;
// A (f32 path) reg-staged + converted, ds_write at swizzled offset.
template<int A_IS_F32, int RELU_F32_OUT>
__global__ __launch_bounds__(512, 4) void gemm_bt_kernel(
    const void* __restrict__ Av, const bf16_t* __restrict__ Bt,
    void* __restrict__ Cv, int K, int lda, int ldb, int ldc, int ntiles) {
  constexpr int BM = 128, BN = 64, BK = 64;
  __shared__ alignas(16) bf16_t Al[2][BM * BK];
  __shared__ alignas(16) bf16_t Bl[2][BN * BK];

  const int tid  = threadIdx.x;
  const int lane = tid & 63;
  const int w    = tid >> 6;
  const int wr   = w >> 1;  // 0..3 (M)
  const int wc   = w & 1;   // 0..1 (N)

  // XCD-chunked swizzle (grid divisible by 8): the 8 n-tiles sharing an adj
  // row-band get consecutive slots on ONE XCD -> L2 reuse of the A band.
  const int nwg = gridDim.x;
  const int cpx = nwg >> 3;
  const int bid = blockIdx.x;
  const int swz = (bid & 7) * cpx + (bid >> 3);
  const int mt = swz / ntiles;
  const int nt = swz - mt * ntiles;
  const int row0 = mt * BM;
  const int col0 = nt * BN;

  f32x4 acc[2][2];
  #pragma unroll
  for (int mi = 0; mi < 2; ++mi)
    #pragma unroll
    for (int ni = 0; ni < 2; ++ni)
      acc[mi][ni] = (f32x4){0.f, 0.f, 0.f, 0.f};

  const float*  Af = (const float*)Av;
  const bf16_t* Ab = (const bf16_t*)Av;

  // staging geometry: row = tid>>3 (0..63), 16B chunk = tid&7, source swizzled
  const int brow = tid >> 3;
  const int bc8  = tid & 7;
  const int bc8s = bc8 ^ (brow & 7);

  // A reg-staging geometry (f32 path): 4 float4 chunks per thread (128x64 f32)
  int arow[4], ac4[4], awofs[4];
  f32x4 apref[4];
  if constexpr (A_IS_F32) {
    #pragma unroll
    for (int i = 0; i < 4; ++i) {
      int idx = tid + i * 512;
      arow[i] = idx >> 4;   // 0..127
      ac4[i]  = idx & 15;   // f32x4 chunk within row (16 per row)
      awofs[i] = arow[i] * 64 + (((ac4[i] >> 1) ^ (arow[i] & 7)) << 3) + (ac4[i] & 1) * 4;
    }
  }

  const int nkt = K / BK;

  auto stageB = [&](int b, int k0) {
    // 64x64 bf16 = 8 KB = 512 x 16B chunks: exactly one per thread
    gload_lds16(&Bt[(size_t)(col0 + brow) * ldb + k0 + bc8s * 8], &Bl[b][tid * 8]);
  };
  auto stageA16 = [&](int b, int k0) {
    // 128x64 bf16 = 16 KB: two 16B chunks per thread (rows r and r+64)
    gload_lds16(&Ab[(size_t)(row0 + brow) * lda + k0 + bc8s * 8], &Al[b][tid * 8]);
    gload_lds16(&Ab[(size_t)(row0 + brow + 64) * lda + k0 + bc8s * 8], &Al[b][tid * 8 + 64 * 64]);
  };
  auto loadA = [&](int k0) {
    #pragma unroll
    for (int i = 0; i < 4; ++i)
      apref[i] = *(const f32x4*)&Af[(size_t)(row0 + arow[i]) * lda + k0 + ac4[i] * 4];
  };
  auto writeA = [&](int b) {
    #pragma unroll
    for (int i = 0; i < 4; ++i) {
      bf16x4 v;
      v[0] = (bf16_t)apref[i][0]; v[1] = (bf16_t)apref[i][1];
      v[2] = (bf16_t)apref[i][2]; v[3] = (bf16_t)apref[i][3];
      *(bf16x4*)&Al[b][awofs[i]] = v;
    }
  };

  // ---- prologue: fill buffer 0, preload A regs for tile 1 ----
  stageB(0, 0);
  if constexpr (A_IS_F32) {
    loadA(0);
    writeA(0);
    if (nkt > 1) loadA(BK);
  } else {
    stageA16(0, 0);
  }
  __syncthreads();

  int cur = 0;
  for (int kt = 0; kt < nkt; ++kt) {
    // phase 1: issue next-tile staging into buf^1 (drains at end-of-step barrier)
    if (kt + 1 < nkt) {
      stageB(cur ^ 1, (kt + 1) * BK);
      if constexpr (A_IS_F32) {
        writeA(cur ^ 1);                        // apref holds tile kt+1
        if (kt + 2 < nkt) loadA((kt + 2) * BK); // issue loads for tile kt+2
      } else {
        stageA16(cur ^ 1, (kt + 1) * BK);
      }
    }
    // phase 2: compute on buf cur
    #pragma unroll
    for (int kk = 0; kk < 2; ++kk) {
      bf16x8 a[2], b[2];
      const int c16 = kk * 4 + (lane >> 4);
      #pragma unroll
      for (int mi = 0; mi < 2; ++mi) {
        const int r = wr * 32 + mi * 16 + (lane & 15);
        a[mi] = *(const bf16x8*)&Al[cur][r * 64 + ((c16 ^ (r & 7)) << 3)];
      }
      #pragma unroll
      for (int ni = 0; ni < 2; ++ni) {
        const int r = wc * 32 + ni * 16 + (lane & 15);
        b[ni] = *(const bf16x8*)&Bl[cur][r * 64 + ((c16 ^ (r & 7)) << 3)];
      }
      #pragma unroll
      for (int mi = 0; mi < 2; ++mi)
        #pragma unroll
        for (int ni = 0; ni < 2; ++ni)
          acc[mi][ni] = __builtin_amdgcn_mfma_f32_16x16x32_bf16(a[mi], b[ni], acc[mi][ni], 0, 0, 0);
    }
    __syncthreads();
    cur ^= 1;
  }

  // epilogue: C/D layout col=lane&15, row=(lane>>4)*4+reg  [m89-verified]
  const int rbase = row0 + wr * 32 + ((lane >> 4) << 2);
  const int cbase = col0 + wc * 32 + (lane & 15);
  if constexpr (RELU_F32_OUT) {
    float* C = (float*)Cv;
    #pragma unroll
    for (int mi = 0; mi < 2; ++mi)
      #pragma unroll
      for (int ni = 0; ni < 2; ++ni)
        #pragma unroll
        for (int j = 0; j < 4; ++j)
          C[(size_t)(rbase + mi * 16 + j) * ldc + cbase + ni * 16] =
              fmaxf(acc[mi][ni][j], 0.0f);
  } else {
    bf16_t* C = (bf16_t*)Cv;
    #pragma unroll
    for (int mi = 0; mi < 2; ++mi)
      #pragma unroll
      for (int ni = 0; ni < 2; ++ni)
        #pragma unroll
        for (int j = 0; j < 4; ++j)
          C[(size_t)(rbase + mi * 16 + j) * ldc + cbase + ni * 16] =
              (bf16_t)acc[mi][ni][j];
  }
}

extern "C" void kernel_launch(void* const* d_in, const int* in_sizes, int n_in,
                              void* d_out, int out_size, void* d_ws, size_t ws_size,
                              hipStream_t stream) {
  const int N = 8192, D = 512;
  const float* features = (const float*)d_in[0];  // [N][D]
  const float* adj      = (const float*)d_in[1];  // [N][N]
  const float* weight   = (const float*)d_in[2];  // [D][D]
  float* out = (float*)d_out;                     // [N][D] f32

  char* ws = (char*)d_ws;
  bf16_t* fb16 = (bf16_t*)ws;                                   // [N][D]   8.4 MB
  bf16_t* wT   = (bf16_t*)(ws + (size_t)N * D * 2);             // [D][D]   0.5 MB
  bf16_t* fwT  = (bf16_t*)(ws + (size_t)N * D * 2 + (size_t)D * D * 2);  // [D][N] 8.4 MB

  // K0a: features f32 -> bf16 (row-major, din-contiguous)
  cvt_f32_bf16_kernel<<<(N * D / 8) / 256, 256, 0, stream>>>(features, fb16);
  // K0b: wT[dout][din] = weight[din][dout], bf16
  transpose_cvt_kernel<<<dim3(16, 16), 256, 0, stream>>>(weight, wT);
  // K1: fwT[dout][node] = sum_din wT[dout][din] * fb16[node][din]
  //     M=512, N=8192, K=512 -> grid 4 * 128 = 512
  gemm_bt_kernel<0, 0><<<512, 512, 0, stream>>>(wT, fb16, fwT,
                                                512, 512, 512, 8192, 128);
  // K2: out[node][dout] = relu( sum_k adj[node][k] * fwT[dout][k] )
  //     M=8192, N=512, K=8192 -> grid 64 * 8 = 512
  gemm_bt_kernel<1, 1><<<512, 512, 0, stream>>>(adj, fwT, out,
                                                8192, 8192, 8192, 512, 8);
}

// Round 4
// 138.992 us; speedup vs baseline: 1.3022x; 1.3022x over previous
//
#include <hip/hip_runtime.h>
#include <hip/hip_bf16.h>
#include <stdint.h>

typedef __bf16 bf16_t;
typedef __bf16 bf16x4 __attribute__((ext_vector_type(4)));
typedef __bf16 bf16x8 __attribute__((ext_vector_type(8)));
typedef float  f32x4  __attribute__((ext_vector_type(4)));

#define AS_GLOBAL __attribute__((address_space(1)))
#define AS_LDS    __attribute__((address_space(3)))

__device__ __forceinline__ void gload_lds16(const void* g, void* l) {
  __builtin_amdgcn_global_load_lds((const AS_GLOBAL void*)g,
                                   (AS_LDS void*)l, 16, 0, 0);
}

// ---------------- K0a: f32 -> bf16 elementwise (8 elems/thread) ----------------
__global__ void cvt_f32_bf16_kernel(const float* __restrict__ in,
                                    bf16_t* __restrict__ out) {
  const int i = blockIdx.x * blockDim.x + threadIdx.x;
  f32x4 v0 = *(const f32x4*)&in[(size_t)i * 8];
  f32x4 v1 = *(const f32x4*)&in[(size_t)i * 8 + 4];
  bf16x8 o;
  o[0] = (bf16_t)v0[0]; o[1] = (bf16_t)v0[1]; o[2] = (bf16_t)v0[2]; o[3] = (bf16_t)v0[3];
  o[4] = (bf16_t)v1[0]; o[5] = (bf16_t)v1[1]; o[6] = (bf16_t)v1[2]; o[7] = (bf16_t)v1[3];
  *(bf16x8*)&out[(size_t)i * 8] = o;
}

// ---------------- K0b: weight [512][512] f32 -> wT [512][512] bf16 (transpose) ----------------
__global__ void transpose_cvt_kernel(const float* __restrict__ in,
                                     bf16_t* __restrict__ out) {
  __shared__ float t[32][33];
  const int ti = blockIdx.x;  // din tile
  const int tj = blockIdx.y;  // dout tile
  const int c = threadIdx.x & 31;
  const int r0 = threadIdx.x >> 5;  // 0..7
  #pragma unroll
  for (int p = 0; p < 4; ++p) {
    int r = r0 + p * 8;
    t[r][c] = in[(size_t)(ti * 32 + r) * 512 + tj * 32 + c];
  }
  __syncthreads();
  #pragma unroll
  for (int p = 0; p < 4; ++p) {
    int r = r0 + p * 8;
    out[(size_t)(tj * 32 + r) * 512 + ti * 32 + c] = (bf16_t)t[c][r];
  }
}

// ---------------- GEMM-BT: C[m][n] (+)= sum_k A[m][k] * Bt[n][k] ----------------
// Tile 128(M) x 256(N) x BK=64; 512 threads = 8 waves as 2M x 4N (64x64/wave).
// Logical tile id (after XCD chunk-swizzle): ks-major, nt, mt-fastest -> each
// XCD owns contiguous mt for ONE (nt,ks) combo; its fwT slice (256x4096 bf16
// = 2 MB) is per-XCD-L2-resident, and adj streams from HBM exactly once.
// K-split (nks blocks per output tile): EPI=1 stores f32 partials (reduce pass
// sums + relu); EPI=2 atomicAdd into pre-zeroed out; EPI=0 bf16 store (K1).
// Swizzled LDS: 16B granule g of row r at slot g^(r&7); B source-preswizzled
// for linear global_load_lds, A reg-staged f32->bf16 with swizzled ds_write.
template<int A_IS_F32, int EPI>
__global__ __launch_bounds__(512, 2) void gemm_bt_kernel(
    const void* __restrict__ Av, const bf16_t* __restrict__ Bt,
    void* __restrict__ Cv, int nmt, int nnt, int ksteps,
    int lda, int ldb, int ldc, size_t pstride) {
  constexpr int BM = 128, BN = 256, BK = 64;
  __shared__ alignas(16) bf16_t Al[2][BM * BK];  // 2 x 16 KB
  __shared__ alignas(16) bf16_t Bl[2][BN * BK];  // 2 x 32 KB

  const int tid  = threadIdx.x;
  const int lane = tid & 63;
  const int w    = tid >> 6;
  const int wr   = w >> 2;  // 0..1 (M)
  const int wc   = w & 3;   // 0..3 (N)

  // XCD chunk-swizzle (grid divisible by 8)
  const int nwg = gridDim.x;
  const int cpx = nwg >> 3;
  const int bid = blockIdx.x;
  const int swz = (bid & 7) * cpx + (bid >> 3);
  const int ks  = swz / (nmt * nnt);
  const int r_  = swz - ks * (nmt * nnt);
  const int nt  = r_ / nmt;
  const int mt  = r_ - nt * nmt;
  const int row0 = mt * BM;
  const int col0 = nt * BN;
  const int kst  = ks * ksteps * BK;   // this block's K start

  f32x4 acc[4][4];
  #pragma unroll
  for (int mi = 0; mi < 4; ++mi)
    #pragma unroll
    for (int ni = 0; ni < 4; ++ni)
      acc[mi][ni] = (f32x4){0.f, 0.f, 0.f, 0.f};

  const float*  Af = (const float*)Av;
  const bf16_t* Ab = (const bf16_t*)Av;

  // staging geometry: granule id c = tid + i*512; row = c>>3, col granule = tid&7
  const int brow = tid >> 3;          // 0..63
  const int bc8  = tid & 7;
  const int bc8s = bc8 ^ (brow & 7);  // row&7 invariant under +64k row steps

  // A reg-staging (f32): 4 f32x4 chunks covering 128 rows x 16 chunks
  int arow[4], ac4[4], awofs[4];
  f32x4 apref[4];
  if constexpr (A_IS_F32) {
    #pragma unroll
    for (int i = 0; i < 4; ++i) {
      int idx = tid + i * 512;
      arow[i] = idx >> 4;   // 0..127
      ac4[i]  = idx & 15;
      awofs[i] = arow[i] * 64 + (((ac4[i] >> 1) ^ (arow[i] & 7)) << 3) + (ac4[i] & 1) * 4;
    }
  }

  auto stageB = [&](int b, int k0) {
    // 256x64 bf16 = 32 KB = 2048 granules: 4 per thread (rows brow + i*64)
    #pragma unroll
    for (int i = 0; i < 4; ++i)
      gload_lds16(&Bt[(size_t)(col0 + brow + i * 64) * ldb + kst + k0 + bc8s * 8],
                  &Bl[b][tid * 8 + i * 4096]);
  };
  auto stageA16 = [&](int b, int k0) {
    // 128x64 bf16 = 16 KB: 2 granules per thread
    gload_lds16(&Ab[(size_t)(row0 + brow) * lda + kst + k0 + bc8s * 8], &Al[b][tid * 8]);
    gload_lds16(&Ab[(size_t)(row0 + brow + 64) * lda + kst + k0 + bc8s * 8],
                &Al[b][tid * 8 + 4096]);
  };
  auto loadA = [&](int k0) {
    #pragma unroll
    for (int i = 0; i < 4; ++i)
      apref[i] = *(const f32x4*)&Af[(size_t)(row0 + arow[i]) * lda + kst + k0 + ac4[i] * 4];
  };
  auto writeA = [&](int b) {
    #pragma unroll
    for (int i = 0; i < 4; ++i) {
      bf16x4 v;
      v[0] = (bf16_t)apref[i][0]; v[1] = (bf16_t)apref[i][1];
      v[2] = (bf16_t)apref[i][2]; v[3] = (bf16_t)apref[i][3];
      *(bf16x4*)&Al[b][awofs[i]] = v;
    }
  };

  // ---- prologue ----
  stageB(0, 0);
  if constexpr (A_IS_F32) {
    loadA(0);
    writeA(0);
    if (ksteps > 1) loadA(BK);
  } else {
    stageA16(0, 0);
  }
  __syncthreads();

  int cur = 0;
  for (int kt = 0; kt < ksteps; ++kt) {
    if (kt + 1 < ksteps) {
      stageB(cur ^ 1, (kt + 1) * BK);
      if constexpr (A_IS_F32) {
        writeA(cur ^ 1);
        if (kt + 2 < ksteps) loadA((kt + 2) * BK);
      } else {
        stageA16(cur ^ 1, (kt + 1) * BK);
      }
    }
    #pragma unroll
    for (int kk = 0; kk < 2; ++kk) {
      const int c16 = kk * 4 + (lane >> 4);
      bf16x8 a[4], b[4];
      #pragma unroll
      for (int mi = 0; mi < 4; ++mi) {
        const int r = wr * 64 + mi * 16 + (lane & 15);
        a[mi] = *(const bf16x8*)&Al[cur][r * 64 + ((c16 ^ (r & 7)) << 3)];
      }
      #pragma unroll
      for (int ni = 0; ni < 4; ++ni) {
        const int r = wc * 64 + ni * 16 + (lane & 15);
        b[ni] = *(const bf16x8*)&Bl[cur][r * 64 + ((c16 ^ (r & 7)) << 3)];
      }
      #pragma unroll
      for (int mi = 0; mi < 4; ++mi)
        #pragma unroll
        for (int ni = 0; ni < 4; ++ni)
          acc[mi][ni] = __builtin_amdgcn_mfma_f32_16x16x32_bf16(a[mi], b[ni], acc[mi][ni], 0, 0, 0);
    }
    __syncthreads();
    cur ^= 1;
  }

  // epilogue: C/D layout col=lane&15, row=(lane>>4)*4+reg  [m89-verified]
  const int rbase = row0 + wr * 64 + ((lane >> 4) << 2);
  const int cbase = col0 + wc * 64 + (lane & 15);
  if constexpr (EPI == 1) {           // f32 partial store (per-ks buffer)
    float* C = (float*)Cv + (size_t)ks * pstride;
    #pragma unroll
    for (int mi = 0; mi < 4; ++mi)
      #pragma unroll
      for (int ni = 0; ni < 4; ++ni)
        #pragma unroll
        for (int j = 0; j < 4; ++j)
          C[(size_t)(rbase + mi * 16 + j) * ldc + cbase + ni * 16] = acc[mi][ni][j];
  } else if constexpr (EPI == 2) {    // atomic accumulate into zeroed out
    float* C = (float*)Cv;
    #pragma unroll
    for (int mi = 0; mi < 4; ++mi)
      #pragma unroll
      for (int ni = 0; ni < 4; ++ni)
        #pragma unroll
        for (int j = 0; j < 4; ++j)
          atomicAdd(&C[(size_t)(rbase + mi * 16 + j) * ldc + cbase + ni * 16],
                    acc[mi][ni][j]);
  } else {                            // bf16 store (K1)
    bf16_t* C = (bf16_t*)Cv;
    #pragma unroll
    for (int mi = 0; mi < 4; ++mi)
      #pragma unroll
      for (int ni = 0; ni < 4; ++ni)
        #pragma unroll
        for (int j = 0; j < 4; ++j)
          C[(size_t)(rbase + mi * 16 + j) * ldc + cbase + ni * 16] =
              (bf16_t)acc[mi][ni][j];
  }
}

// ---------------- reduce two f32 partials + relu ----------------
__global__ void reduce_relu_kernel(const float* __restrict__ p0,
                                   const float* __restrict__ p1,
                                   float* __restrict__ out) {
  const size_t i = ((size_t)blockIdx.x * blockDim.x + threadIdx.x) * 4;
  f32x4 a = *(const f32x4*)&p0[i];
  f32x4 b = *(const f32x4*)&p1[i];
  f32x4 r;
  r[0] = fmaxf(a[0] + b[0], 0.f); r[1] = fmaxf(a[1] + b[1], 0.f);
  r[2] = fmaxf(a[2] + b[2], 0.f); r[3] = fmaxf(a[3] + b[3], 0.f);
  *(f32x4*)&out[i] = r;
}

// ---------------- in-place relu (atomic fallback) ----------------
__global__ void relu_inplace_kernel(float* __restrict__ out) {
  const size_t i = ((size_t)blockIdx.x * blockDim.x + threadIdx.x) * 4;
  f32x4 a = *(const f32x4*)&out[i];
  f32x4 r;
  r[0] = fmaxf(a[0], 0.f); r[1] = fmaxf(a[1], 0.f);
  r[2] = fmaxf(a[2], 0.f); r[3] = fmaxf(a[3], 0.f);
  *(f32x4*)&out[i] = r;
}

extern "C" void kernel_launch(void* const* d_in, const int* in_sizes, int n_in,
                              void* d_out, int out_size, void* d_ws, size_t ws_size,
                              hipStream_t stream) {
  const int N = 8192, D = 512;
  const float* features = (const float*)d_in[0];  // [N][D]
  const float* adj      = (const float*)d_in[1];  // [N][N]
  const float* weight   = (const float*)d_in[2];  // [D][D]
  float* out = (float*)d_out;                     // [N][D] f32

  char* ws = (char*)d_ws;
  bf16_t* fb16 = (bf16_t*)ws;                                    // 8.39 MB
  bf16_t* wT   = (bf16_t*)(ws + (size_t)N * D * 2);              // 0.52 MB
  bf16_t* fwT  = (bf16_t*)(ws + (size_t)N * D * 2 + (size_t)D * D * 2);  // 8.39 MB
  const size_t base_bytes = (size_t)N * D * 2 * 2 + (size_t)D * D * 2;   // 17.3 MB
  float* part = (float*)(ws + base_bytes);        // 2 x 16.78 MB if available
  const size_t pstride = (size_t)N * D;           // elements per partial
  const bool have_part = ws_size >= base_bytes + 2 * pstride * sizeof(float);

  // K0a: features f32 -> bf16
  cvt_f32_bf16_kernel<<<(N * D / 8) / 256, 256, 0, stream>>>(features, fb16);
  // K0b: wT[dout][din] = weight[din][dout]
  transpose_cvt_kernel<<<dim3(16, 16), 256, 0, stream>>>(weight, wT);
  // K1: fwT[dout][node] = wT @ fb16^T   (M=512 -> nmt=4, N=8192 -> nnt=32,
  //     K=512 -> 8 steps, no k-split).  grid = 4*32 = 128
  gemm_bt_kernel<0, 0><<<128, 512, 0, stream>>>(wT, fb16, fwT,
                                                4, 32, 8, 512, 512, 8192, 0);
  // K2: out = relu(adj @ fwT^T)  M=8192 (nmt=64), N=512 (nnt=2), K=8192
  //     k-split 2 (ksteps=64 each) -> grid = 64*2*2 = 256
  if (have_part) {
    gemm_bt_kernel<1, 1><<<256, 512, 0, stream>>>(adj, fwT, part,
                                                  64, 2, 64, 8192, 8192, 512, pstride);
    reduce_relu_kernel<<<(N * D / 4) / 512, 512, 0, stream>>>(part, part + pstride, out);
  } else {
    hipMemsetAsync(d_out, 0, (size_t)N * D * sizeof(float), stream);
    gemm_bt_kernel<1, 2><<<256, 512, 0, stream>>>(adj, fwT, out,
                                                  64, 2, 64, 8192, 8192, 512, 0);
    relu_inplace_kernel<<<(N * D / 4) / 512, 512, 0, stream>>>(out);
  }
}

// Round 5
// 133.084 us; speedup vs baseline: 1.3600x; 1.0444x over previous
//
#include <hip/hip_runtime.h>
#include <hip/hip_bf16.h>
#include <stdint.h>

typedef __bf16 bf16_t;
typedef __bf16 bf16x4 __attribute__((ext_vector_type(4)));
typedef __bf16 bf16x8 __attribute__((ext_vector_type(8)));
typedef float  f32x4  __attribute__((ext_vector_type(4)));

#define AS_GLOBAL __attribute__((address_space(1)))
#define AS_LDS    __attribute__((address_space(3)))

__device__ __forceinline__ void gload_lds16(const void* g, void* l) {
  __builtin_amdgcn_global_load_lds((const AS_GLOBAL void*)g,
                                   (AS_LDS void*)l, 16, 0, 0);
}

// ---------------- K0a: f32 -> bf16 elementwise (8 elems/thread) ----------------
__global__ void cvt_f32_bf16_kernel(const float* __restrict__ in,
                                    bf16_t* __restrict__ out) {
  const int i = blockIdx.x * blockDim.x + threadIdx.x;
  f32x4 v0 = *(const f32x4*)&in[(size_t)i * 8];
  f32x4 v1 = *(const f32x4*)&in[(size_t)i * 8 + 4];
  bf16x8 o;
  o[0] = (bf16_t)v0[0]; o[1] = (bf16_t)v0[1]; o[2] = (bf16_t)v0[2]; o[3] = (bf16_t)v0[3];
  o[4] = (bf16_t)v1[0]; o[5] = (bf16_t)v1[1]; o[6] = (bf16_t)v1[2]; o[7] = (bf16_t)v1[3];
  *(bf16x8*)&out[(size_t)i * 8] = o;
}

// ---------------- K0b: weight [512][512] f32 -> wT [512][512] bf16 (transpose) ----------------
__global__ void transpose_cvt_kernel(const float* __restrict__ in,
                                     bf16_t* __restrict__ out) {
  __shared__ float t[32][33];
  const int ti = blockIdx.x;  // din tile
  const int tj = blockIdx.y;  // dout tile
  const int c = threadIdx.x & 31;
  const int r0 = threadIdx.x >> 5;  // 0..7
  #pragma unroll
  for (int p = 0; p < 4; ++p) {
    int r = r0 + p * 8;
    t[r][c] = in[(size_t)(ti * 32 + r) * 512 + tj * 32 + c];
  }
  __syncthreads();
  #pragma unroll
  for (int p = 0; p < 4; ++p) {
    int r = r0 + p * 8;
    out[(size_t)(tj * 32 + r) * 512 + ti * 32 + c] = (bf16_t)t[c][r];
  }
}

// ---------------- GEMM-BT: C[m][n] (+)= sum_k A[m][k] * Bt[n][k] ----------------
// BM=128, BK=32, BN = NI*64; 512 threads = 8 waves as 2M x 4N; wave tile
// 64 x NI*16, acc[4][NI]. Rows are 64 B in LDS (4 x 16B granules); granule g
// of row r lives at slot g^(r&3) -> conflict-free b128 frag reads.
// B staged by global_load_lds (linear dest, SOURCE granule pre-swizzled);
// A is either bf16 (gload_lds) or f32 (reg-staged + cvt, swizzled ds_write,
// 1-step-ahead HBM prefetch). Stage-ahead double-buffer, 1 barrier/step.
// K-split: block ks covers K-range [ks*ksteps*32, ...). XCD chunk-swizzle is
// ks-major so each XCD's Bt K-slice stays L2-resident while A streams once.
// EPI: 0 = bf16 store; 2 = f32 atomicAdd into pre-zeroed Cv; 3 = bf16 partial
// store at Cv + ks*pstride.
template<int A_IS_F32, int EPI, int NI>
__global__ __launch_bounds__(512, 2) void gemm_bt32_kernel(
    const void* __restrict__ Av, const bf16_t* __restrict__ Bt,
    void* __restrict__ Cv, int nmt, int nnt, int ksteps,
    int lda, int ldb, int ldc, size_t pstride) {
  constexpr int BM = 128, BK = 32, BN = NI * 64;
  __shared__ alignas(16) bf16_t Al[2][BM * BK];  // 2 x 8 KB
  __shared__ alignas(16) bf16_t Bl[2][BN * BK];  // 2 x BN/16 KB

  const int tid  = threadIdx.x;
  const int lane = tid & 63;
  const int w    = tid >> 6;
  const int wr   = w >> 2;  // 0..1 (M)
  const int wc   = w & 3;   // 0..3 (N)

  // XCD chunk-swizzle (grid divisible by 8), ks-major ordering
  const int nwg = gridDim.x;
  const int cpx = nwg >> 3;
  const int bid = blockIdx.x;
  const int swz = (bid & 7) * cpx + (bid >> 3);
  const int ks  = swz / (nmt * nnt);
  const int r_  = swz - ks * (nmt * nnt);
  const int nt  = r_ / nmt;
  const int mt  = r_ - nt * nmt;
  const int row0 = mt * BM;
  const int col0 = nt * BN;
  const int kst  = ks * ksteps * BK;

  f32x4 acc[4][NI];
  #pragma unroll
  for (int mi = 0; mi < 4; ++mi)
    #pragma unroll
    for (int ni = 0; ni < NI; ++ni)
      acc[mi][ni] = (f32x4){0.f, 0.f, 0.f, 0.f};

  const float*  Af = (const float*)Av;
  const bf16_t* Ab = (const bf16_t*)Av;

  // staging geometry: granule d = tid + i*512; row = d>>2, slot = d&3,
  // global source granule = slot ^ (row&3)  (row&3 invariant under +128 rows)
  const int r4   = tid >> 2;          // 0..127
  const int g4   = tid & 3;
  const int gsrc = g4 ^ (r4 & 3);

  f32x4 apref0, apref1;

  auto stageB = [&](int b, int k0) {
    #pragma unroll
    for (int i = 0; i < NI / 2; ++i)
      gload_lds16(&Bt[(size_t)(col0 + r4 + i * 128) * ldb + kst + k0 + gsrc * 8],
                  &Bl[b][(tid + i * 512) * 8]);
  };
  auto stageA16 = [&](int b, int k0) {
    gload_lds16(&Ab[(size_t)(row0 + r4) * lda + kst + k0 + gsrc * 8],
                &Al[b][tid * 8]);
  };
  auto loadA = [&](int k0) {
    const float* p = &Af[(size_t)(row0 + r4) * lda + kst + k0 + g4 * 8];
    apref0 = *(const f32x4*)p;
    apref1 = *(const f32x4*)(p + 4);
  };
  auto writeA = [&](int b) {
    bf16x8 v;
    v[0] = (bf16_t)apref0[0]; v[1] = (bf16_t)apref0[1];
    v[2] = (bf16_t)apref0[2]; v[3] = (bf16_t)apref0[3];
    v[4] = (bf16_t)apref1[0]; v[5] = (bf16_t)apref1[1];
    v[6] = (bf16_t)apref1[2]; v[7] = (bf16_t)apref1[3];
    *(bf16x8*)&Al[b][r4 * 32 + ((g4 ^ (r4 & 3)) << 3)] = v;
  };

  // ---- prologue ----
  stageB(0, 0);
  if constexpr (A_IS_F32) {
    loadA(0);
    writeA(0);
    if (ksteps > 1) loadA(BK);
  } else {
    stageA16(0, 0);
  }
  __syncthreads();

  int cur = 0;
  for (int kt = 0; kt < ksteps; ++kt) {
    if (kt + 1 < ksteps) {
      stageB(cur ^ 1, (kt + 1) * BK);
      if constexpr (A_IS_F32) {
        writeA(cur ^ 1);                        // apref holds tile kt+1
        if (kt + 2 < ksteps) loadA((kt + 2) * BK);
      } else {
        stageA16(cur ^ 1, (kt + 1) * BK);
      }
    }
    // frags: k-granule = lane>>4
    const int frow = lane & 15;
    const int gk = lane >> 4;
    bf16x8 a[4], b[NI];
    #pragma unroll
    for (int mi = 0; mi < 4; ++mi) {
      const int r = wr * 64 + mi * 16 + frow;
      a[mi] = *(const bf16x8*)&Al[cur][r * 32 + ((gk ^ (r & 3)) << 3)];
    }
    #pragma unroll
    for (int ni = 0; ni < NI; ++ni) {
      const int r = wc * (NI * 16) + ni * 16 + frow;
      b[ni] = *(const bf16x8*)&Bl[cur][r * 32 + ((gk ^ (r & 3)) << 3)];
    }
    #pragma unroll
    for (int mi = 0; mi < 4; ++mi)
      #pragma unroll
      for (int ni = 0; ni < NI; ++ni)
        acc[mi][ni] = __builtin_amdgcn_mfma_f32_16x16x32_bf16(a[mi], b[ni], acc[mi][ni], 0, 0, 0);
    __syncthreads();
    cur ^= 1;
  }

  // epilogue: C/D layout col=lane&15, row=(lane>>4)*4+reg  [m89-verified]
  const int rbase = row0 + wr * 64 + ((lane >> 4) << 2);
  const int cbase = col0 + wc * (NI * 16) + (lane & 15);
  if constexpr (EPI == 3) {           // bf16 partial store (per-ks buffer)
    bf16_t* C = (bf16_t*)Cv + (size_t)ks * pstride;
    #pragma unroll
    for (int mi = 0; mi < 4; ++mi)
      #pragma unroll
      for (int ni = 0; ni < NI; ++ni)
        #pragma unroll
        for (int j = 0; j < 4; ++j)
          C[(size_t)(rbase + mi * 16 + j) * ldc + cbase + ni * 16] =
              (bf16_t)acc[mi][ni][j];
  } else if constexpr (EPI == 2) {    // atomic accumulate into zeroed out
    float* C = (float*)Cv;
    #pragma unroll
    for (int mi = 0; mi < 4; ++mi)
      #pragma unroll
      for (int ni = 0; ni < NI; ++ni)
        #pragma unroll
        for (int j = 0; j < 4; ++j)
          atomicAdd(&C[(size_t)(rbase + mi * 16 + j) * ldc + cbase + ni * 16],
                    acc[mi][ni][j]);
  } else {                            // bf16 store (K1)
    bf16_t* C = (bf16_t*)Cv;
    #pragma unroll
    for (int mi = 0; mi < 4; ++mi)
      #pragma unroll
      for (int ni = 0; ni < NI; ++ni)
        #pragma unroll
        for (int j = 0; j < 4; ++j)
          C[(size_t)(rbase + mi * 16 + j) * ldc + cbase + ni * 16] =
              (bf16_t)acc[mi][ni][j];
  }
}

// ---------------- reduce 4 bf16 partials + relu -> f32 ----------------
__global__ void reduce4_relu_kernel(const bf16_t* __restrict__ part,
                                    size_t pstride, float* __restrict__ out) {
  const size_t i8 = ((size_t)blockIdx.x * blockDim.x + threadIdx.x) * 8;
  float s[8];
  #pragma unroll
  for (int j = 0; j < 8; ++j) s[j] = 0.f;
  #pragma unroll
  for (int p = 0; p < 4; ++p) {
    bf16x8 v = *(const bf16x8*)&part[p * pstride + i8];
    #pragma unroll
    for (int j = 0; j < 8; ++j) s[j] += (float)v[j];
  }
  f32x4 r0, r1;
  r0[0] = fmaxf(s[0], 0.f); r0[1] = fmaxf(s[1], 0.f);
  r0[2] = fmaxf(s[2], 0.f); r0[3] = fmaxf(s[3], 0.f);
  r1[0] = fmaxf(s[4], 0.f); r1[1] = fmaxf(s[5], 0.f);
  r1[2] = fmaxf(s[6], 0.f); r1[3] = fmaxf(s[7], 0.f);
  *(f32x4*)&out[i8] = r0;
  *(f32x4*)&out[i8 + 4] = r1;
}

// ---------------- in-place relu (atomic fallback) ----------------
__global__ void relu_inplace_kernel(float* __restrict__ out) {
  const size_t i = ((size_t)blockIdx.x * blockDim.x + threadIdx.x) * 4;
  f32x4 a = *(const f32x4*)&out[i];
  f32x4 r;
  r[0] = fmaxf(a[0], 0.f); r[1] = fmaxf(a[1], 0.f);
  r[2] = fmaxf(a[2], 0.f); r[3] = fmaxf(a[3], 0.f);
  *(f32x4*)&out[i] = r;
}

extern "C" void kernel_launch(void* const* d_in, const int* in_sizes, int n_in,
                              void* d_out, int out_size, void* d_ws, size_t ws_size,
                              hipStream_t stream) {
  const int N = 8192, D = 512;
  const float* features = (const float*)d_in[0];  // [N][D]
  const float* adj      = (const float*)d_in[1];  // [N][N]
  const float* weight   = (const float*)d_in[2];  // [D][D]
  float* out = (float*)d_out;                     // [N][D] f32

  char* ws = (char*)d_ws;
  bf16_t* fb16 = (bf16_t*)ws;                                    // 8.39 MB
  bf16_t* wT   = (bf16_t*)(ws + (size_t)N * D * 2);              // 0.52 MB
  bf16_t* fwT  = (bf16_t*)(ws + (size_t)N * D * 2 + (size_t)D * D * 2);  // 8.39 MB
  const size_t base_bytes = (size_t)N * D * 2 * 2 + (size_t)D * D * 2;   // 17.3 MB
  bf16_t* part = (bf16_t*)(ws + base_bytes);      // 4 x 8.39 MB bf16 partials
  const size_t pstride = (size_t)N * D;           // elements per partial
  const bool have_part = ws_size >= base_bytes + 4 * pstride * sizeof(bf16_t);

  // K0a: features f32 -> bf16
  cvt_f32_bf16_kernel<<<(N * D / 8) / 256, 256, 0, stream>>>(features, fb16);
  // K0b: wT[dout][din] = weight[din][dout]
  transpose_cvt_kernel<<<dim3(16, 16), 256, 0, stream>>>(weight, wT);
  // K1: fwT[dout][node] = wT @ fb16^T   M=512 (nmt=4), N=8192 (nnt=64, BN=128),
  //     K=512 (16 steps, no k-split).  grid = 4*64 = 256
  gemm_bt32_kernel<0, 0, 2><<<256, 512, 0, stream>>>(wT, fb16, fwT,
                                                     4, 64, 16, 512, 512, 8192, 0);
  // K2: relu(adj @ fwT^T): M=8192 (nmt=64), N=512 (nnt=1, BN=512), K=8192,
  //     k-split 4 (ksteps=64) -> grid = 64*4 = 256; bf16 partials + reduce
  if (have_part) {
    gemm_bt32_kernel<1, 3, 8><<<256, 512, 0, stream>>>(adj, fwT, part,
                                                       64, 1, 64, 8192, 8192, 512, pstride);
    reduce4_relu_kernel<<<(N * D / 8) / 512, 512, 0, stream>>>(part, pstride, out);
  } else {
    hipMemsetAsync(d_out, 0, (size_t)N * D * sizeof(float), stream);
    gemm_bt32_kernel<1, 2, 8><<<256, 512, 0, stream>>>(adj, fwT, out,
                                                       64, 1, 64, 8192, 8192, 512, 0);
    relu_inplace_kernel<<<(N * D / 4) / 512, 512, 0, stream>>>(out);
  }
}